// Round 3
// baseline (290.652 us; speedup 1.0000x reference)
//
#include <hip/hip_runtime.h>
#include <hip/hip_bf16.h>
#include <stdint.h>

// B=2, S=2048, E=1024, H=16, DK=64, causal. Device buffers are FLOAT32
// (npz-size evidence); internal compute bf16 MFMA with f32 accumulation.
// ws intermediates (Q, K, VT, attn-out) are bf16.

typedef __attribute__((ext_vector_type(4))) float f32x4;
typedef __attribute__((ext_vector_type(8))) __bf16 bf16x8;
typedef unsigned short u16;

#define LOG2E 1.4426950408889634f

__device__ __forceinline__ float bf2f(u16 u) {
  union { float f; uint32_t i; } v; v.i = ((uint32_t)u) << 16; return v.f;
}
__device__ __forceinline__ u16 f2bf(float f) {
  union { float f; uint32_t i; } v; v.f = f;
  return (u16)((v.i + 0x7fffu + ((v.i >> 16) & 1u)) >> 16);
}

__device__ __forceinline__ void gload_lds16(const u16* g, u16* l) {
  __builtin_amdgcn_global_load_lds((const __attribute__((address_space(1))) void*)g,
                                   (__attribute__((address_space(3))) void*)l, 16, 0, 0);
}

// Fragment read from [rows][64]-bf16 LDS tile, 16B-slot XOR swizzle slot^=(row&7).
__device__ __forceinline__ bf16x8 ld_frag(const u16* ls, int row, int kh, int lane) {
  int sl = ((kh << 2) | (lane >> 4)) ^ (row & 7);
  return *(const bf16x8*)(ls + row * 64 + sl * 8);
}

__device__ __forceinline__ bf16x8 cvt8(f32x4 a, f32x4 b) {
  union { u16 u[8]; bf16x8 v; } o;
#pragma unroll
  for (int j = 0; j < 4; ++j) { o.u[j] = f2bf(a[j]); o.u[4 + j] = f2bf(b[j]); }
  return o.v;
}

// ---------------------------------------------------------------------------
// GEMM-BT: C[M][N] = A[M][K] * Bw[N][K]^T + bias[N]
// AF32/BF32: operand dtype. f32 operands reg-staged (load f32 -> cvt -> ds_write,
// T14 issue-early/write-late). bf16 operands staged via global_load_lds w16
// with pre-swizzled global source. Read side: XOR-swizzled ds_read_b128.
// MODE 0: N=3072 QKV -> Q[bh][s][64], K[bh][s][64], VT[bh][64][s] (bf16)
// MODE 1: N=1024 out-proj -> f32 [M][1024]
// ---------------------------------------------------------------------------
template <int MODE, bool AF32, bool BF32>
__global__ __launch_bounds__(256, 2) void gemm_bt(
    const void* Ap, const void* Bp, const float* __restrict__ bias,
    void* out0, u16* __restrict__ out1, u16* __restrict__ out2, int K) {
  __shared__ __align__(16) u16 lsA[2][128 * 64];
  __shared__ __align__(16) u16 lsB[2][128 * 64];
  const float* Af = (const float*)Ap; const u16* Ab = (const u16*)Ap;
  const float* Bf = (const float*)Bp; const u16* Bb = (const u16*)Bp;
  const int tid = threadIdx.x, lane = tid & 63, wid = tid >> 6;
  const int bn = blockIdx.x, bm = blockIdx.y;
  const int rowA0 = bm * 128, rowB0 = bn * 128;
  const int wm = wid >> 1, wn = wid & 1;

  f32x4 ra[4][2], rb[4][2];  // in-flight f32 staging regs (next tile)

  auto issue = [&](int buf, int k0) {
    if constexpr (AF32) {
#pragma unroll
      for (int i = 0; i < 4; ++i) {
        int u = i * 256 + tid, r = u >> 3, s = u & 7;
        const float* p = Af + (size_t)(rowA0 + r) * K + k0 + s * 8;
        ra[i][0] = *(const f32x4*)p; ra[i][1] = *(const f32x4*)(p + 4);
      }
    } else {
#pragma unroll
      for (int i = 0; i < 4; ++i) {
        int u = i * 256 + tid, r = u >> 3, s = u & 7;
        int gk = k0 + ((s ^ (r & 7)) << 3);
        gload_lds16(Ab + (size_t)(rowA0 + r) * K + gk,
                    &lsA[buf][(i * 256 + wid * 64) << 3]);
      }
    }
    if constexpr (BF32) {
#pragma unroll
      for (int i = 0; i < 4; ++i) {
        int u = i * 256 + tid, r = u >> 3, s = u & 7;
        const float* p = Bf + (size_t)(rowB0 + r) * K + k0 + s * 8;
        rb[i][0] = *(const f32x4*)p; rb[i][1] = *(const f32x4*)(p + 4);
      }
    } else {
#pragma unroll
      for (int i = 0; i < 4; ++i) {
        int u = i * 256 + tid, r = u >> 3, s = u & 7;
        int gk = k0 + ((s ^ (r & 7)) << 3);
        gload_lds16(Bb + (size_t)(rowB0 + r) * K + gk,
                    &lsB[buf][(i * 256 + wid * 64) << 3]);
      }
    }
  };
  auto commit = [&](int buf) {
    if constexpr (AF32) {
#pragma unroll
      for (int i = 0; i < 4; ++i) {
        int u = i * 256 + tid, r = u >> 3, s = u & 7;
        *(bf16x8*)&lsA[buf][r * 64 + ((s ^ (r & 7)) << 3)] = cvt8(ra[i][0], ra[i][1]);
      }
    }
    if constexpr (BF32) {
#pragma unroll
      for (int i = 0; i < 4; ++i) {
        int u = i * 256 + tid, r = u >> 3, s = u & 7;
        *(bf16x8*)&lsB[buf][r * 64 + ((s ^ (r & 7)) << 3)] = cvt8(rb[i][0], rb[i][1]);
      }
    }
  };

  f32x4 acc[4][4] = {};
  const int NT = K >> 6;
  issue(0, 0);
  commit(0);
  asm volatile("s_waitcnt vmcnt(0)" ::: "memory");
  __syncthreads();
  int cur = 0;
  for (int t = 0; t < NT; ++t) {
    if (t + 1 < NT) issue(cur ^ 1, (t + 1) << 6);  // loads fly during compute
    const u16* la = lsA[cur];
    const u16* lb = lsB[cur];
    bf16x8 af[4][2], bf[4][2];
#pragma unroll
    for (int m = 0; m < 4; ++m) {
      int row = wm * 64 + m * 16 + (lane & 15);
#pragma unroll
      for (int kh = 0; kh < 2; ++kh) af[m][kh] = ld_frag(la, row, kh, lane);
    }
#pragma unroll
    for (int n = 0; n < 4; ++n) {
      int row = wn * 64 + n * 16 + (lane & 15);
#pragma unroll
      for (int kh = 0; kh < 2; ++kh) bf[n][kh] = ld_frag(lb, row, kh, lane);
    }
#pragma unroll
    for (int m = 0; m < 4; ++m)
#pragma unroll
      for (int n = 0; n < 4; ++n)
#pragma unroll
        for (int kh = 0; kh < 2; ++kh)
          acc[m][n] = __builtin_amdgcn_mfma_f32_16x16x32_bf16(af[m][kh], bf[n][kh], acc[m][n], 0, 0, 0);
    if (t + 1 < NT) commit(cur ^ 1);  // write-late: cvt + ds_write next tile
    __syncthreads();                  // drains vmcnt+lgkm: next buffer ready
    cur ^= 1;
  }

  // epilogue: C/D layout col=lane&15, row=(lane>>4)*4+reg  [m91-verified]
#pragma unroll
  for (int m = 0; m < 4; ++m) {
    int gRow0 = rowA0 + wm * 64 + m * 16 + ((lane >> 4) << 2);
#pragma unroll
    for (int n = 0; n < 4; ++n) {
      int gCol = rowB0 + wn * 64 + n * 16 + (lane & 15);
      float bv = bias[gCol];
      if (MODE == 0) {
        int sec = gCol >> 10, e = gCol & 1023;
        int h = e >> 6, d = e & 63;
        int b = gRow0 >> 11, s0 = gRow0 & 2047;
        int bh = b * 16 + h;
        if (sec == 2) {
          union { u16 u[4]; uint64_t q; } pk;
#pragma unroll
          for (int r = 0; r < 4; ++r) pk.u[r] = f2bf(acc[m][n][r] + bv);
          *(uint64_t*)&out2[((size_t)bh * 64 + d) * 2048 + s0] = pk.q;
        } else {
          u16* dst = (sec == 0) ? (u16*)out0 : out1;
#pragma unroll
          for (int r = 0; r < 4; ++r)
            dst[((size_t)bh * 2048 + (s0 + r)) * 64 + d] = f2bf(acc[m][n][r] + bv);
        }
      } else {
        float* O = (float*)out0;
#pragma unroll
        for (int r = 0; r < 4; ++r)
          O[(size_t)(gRow0 + r) * 1024 + gCol] = acc[m][n][r] + bv;
      }
    }
  }
}

// ---------------------------------------------------------------------------
// Flash attention, causal. Block = (bh, qtile of 128 rows), 4 waves x 32 rows.
// All-bf16 ws tensors; unchanged structure.
// ---------------------------------------------------------------------------
__global__ __launch_bounds__(256, 2) void attn_kernel(
    const u16* __restrict__ Q, const u16* __restrict__ Kt,
    const u16* __restrict__ VT, u16* __restrict__ attn) {
  __shared__ __align__(16) u16 lsK[2][64 * 64];
  __shared__ __align__(16) u16 lsV[2][64 * 64];
  __shared__ __align__(16) u16 lsP[128 * 64];
  const int tid = threadIdx.x, lane = tid & 63, wid = tid >> 6;
  const int qt = blockIdx.x, bh = blockIdx.y;
  const int b = bh >> 4, h = bh & 15;
  const u16* Qb = Q + (size_t)bh * 2048 * 64;
  const u16* Kb = Kt + (size_t)bh * 2048 * 64;
  const u16* Vb = VT + (size_t)bh * 64 * 2048;
  const int qRow0 = qt * 128 + wid * 32;

  bf16x8 qf[2][2];
#pragma unroll
  for (int m = 0; m < 2; ++m) {
    int row = qRow0 + m * 16 + (lane & 15);
#pragma unroll
    for (int kh = 0; kh < 2; ++kh) {
      int d0 = kh * 32 + ((lane >> 4) << 3);
      qf[m][kh] = *(const bf16x8*)(Qb + (size_t)row * 64 + d0);
    }
  }

  float rowmax[2][4], rowsum[2][4];
  f32x4 acc_o[2][4] = {};
#pragma unroll
  for (int m = 0; m < 2; ++m)
#pragma unroll
    for (int r = 0; r < 4; ++r) { rowmax[m][r] = -1e30f; rowsum[m][r] = 0.f; }

  auto stageKV = [&](int buf, int kt) {
#pragma unroll
    for (int i = 0; i < 2; ++i) {
      int u = i * 256 + tid;
      int r = u >> 3, s = u & 7;
      int gk = ((s ^ (r & 7)) << 3);
      gload_lds16(Kb + (size_t)(kt * 64 + r) * 64 + gk,
                  &lsK[buf][(i * 256 + wid * 64) << 3]);
    }
#pragma unroll
    for (int i = 0; i < 2; ++i) {
      int u = i * 256 + tid;
      int r = u >> 3, s = u & 7;
      int gk = kt * 64 + ((s ^ (r & 7)) << 3);
      gload_lds16(Vb + (size_t)r * 2048 + gk,
                  &lsV[buf][(i * 256 + wid * 64) << 3]);
    }
  };

  const int NT = qt * 2 + 2;
  stageKV(0, 0);
  asm volatile("s_waitcnt vmcnt(0)" ::: "memory");
  __syncthreads();
  int cur = 0;
  for (int kt = 0; kt < NT; ++kt) {
    if (kt + 1 < NT) stageKV(cur ^ 1, kt + 1);

    f32x4 sc[2][4] = {};
    bf16x8 kf[4][2];
#pragma unroll
    for (int n = 0; n < 4; ++n) {
      int row = n * 16 + (lane & 15);
#pragma unroll
      for (int kh = 0; kh < 2; ++kh) kf[n][kh] = ld_frag(lsK[cur], row, kh, lane);
    }
#pragma unroll
    for (int m = 0; m < 2; ++m)
#pragma unroll
      for (int n = 0; n < 4; ++n)
#pragma unroll
        for (int kh = 0; kh < 2; ++kh)
          sc[m][n] = __builtin_amdgcn_mfma_f32_16x16x32_bf16(qf[m][kh], kf[n][kh], sc[m][n], 0, 0, 0);

    const bool maskTile = (kt * 64 + 63) > qRow0;
    float tmax[2][4];
#pragma unroll
    for (int m = 0; m < 2; ++m) {
#pragma unroll
      for (int r = 0; r < 4; ++r) tmax[m][r] = -1e30f;
#pragma unroll
      for (int n = 0; n < 4; ++n)
#pragma unroll
        for (int r = 0; r < 4; ++r) {
          float s = sc[m][n][r] * 0.125f;
          if (maskTile) {
            int qrow = qRow0 + m * 16 + ((lane >> 4) << 2) + r;
            int kcol = kt * 64 + n * 16 + (lane & 15);
            if (kcol > qrow) s = -1e30f;
          }
          sc[m][n][r] = s;
          tmax[m][r] = fmaxf(tmax[m][r], s);
        }
#pragma unroll
      for (int r = 0; r < 4; ++r) {
        float v = tmax[m][r];
        v = fmaxf(v, __shfl_xor(v, 1));
        v = fmaxf(v, __shfl_xor(v, 2));
        v = fmaxf(v, __shfl_xor(v, 4));
        v = fmaxf(v, __shfl_xor(v, 8));
        tmax[m][r] = v;
      }
    }

#pragma unroll
    for (int m = 0; m < 2; ++m) {
      float psum[4] = {0.f, 0.f, 0.f, 0.f};
#pragma unroll
      for (int r = 0; r < 4; ++r) {
        float mnew = fmaxf(rowmax[m][r], tmax[m][r]);
        float rs = exp2f((rowmax[m][r] - mnew) * LOG2E);
        rowmax[m][r] = mnew;
        rowsum[m][r] *= rs;
#pragma unroll
        for (int n = 0; n < 4; ++n) acc_o[m][n][r] *= rs;
      }
#pragma unroll
      for (int n = 0; n < 4; ++n)
#pragma unroll
        for (int r = 0; r < 4; ++r) {
          float p = exp2f((sc[m][n][r] - rowmax[m][r]) * LOG2E);
          psum[r] += p;
          int rowl = wid * 32 + m * 16 + ((lane >> 4) << 2) + r;
          int col = n * 16 + (lane & 15);
          int sl = (col >> 3) ^ (rowl & 7);
          lsP[rowl * 64 + sl * 8 + (col & 7)] = f2bf(p);
        }
#pragma unroll
      for (int r = 0; r < 4; ++r) {
        float v = psum[r];
        v += __shfl_xor(v, 1); v += __shfl_xor(v, 2);
        v += __shfl_xor(v, 4); v += __shfl_xor(v, 8);
        rowsum[m][r] += v;
      }
    }

    bf16x8 pf[2][2], vf[4][2];
#pragma unroll
    for (int n = 0; n < 4; ++n) {
      int row = n * 16 + (lane & 15);
#pragma unroll
      for (int kh = 0; kh < 2; ++kh) vf[n][kh] = ld_frag(lsV[cur], row, kh, lane);
    }
#pragma unroll
    for (int m = 0; m < 2; ++m) {
      int row = wid * 32 + m * 16 + (lane & 15);
#pragma unroll
      for (int kh = 0; kh < 2; ++kh) pf[m][kh] = ld_frag(lsP, row, kh, lane);
    }
#pragma unroll
    for (int m = 0; m < 2; ++m)
#pragma unroll
      for (int n = 0; n < 4; ++n)
#pragma unroll
        for (int kh = 0; kh < 2; ++kh)
          acc_o[m][n] = __builtin_amdgcn_mfma_f32_16x16x32_bf16(pf[m][kh], vf[n][kh], acc_o[m][n], 0, 0, 0);

    __syncthreads();
    cur ^= 1;
  }

#pragma unroll
  for (int m = 0; m < 2; ++m)
#pragma unroll
    for (int r = 0; r < 4; ++r) {
      float inv = 1.0f / rowsum[m][r];
      int srow = qt * 128 + wid * 32 + m * 16 + ((lane >> 4) << 2) + r;
#pragma unroll
      for (int n = 0; n < 4; ++n) {
        int d = n * 16 + (lane & 15);
        attn[((size_t)(b * 2048 + srow)) * 1024 + h * 64 + d] = f2bf(acc_o[m][n][r] * inv);
      }
    }
}

extern "C" void kernel_launch(void* const* d_in, const int* in_sizes, int n_in,
                              void* d_out, int out_size, void* d_ws, size_t ws_size,
                              hipStream_t stream) {
  const float* x     = (const float*)d_in[0];
  const float* w_in  = (const float*)d_in[1];
  const float* b_in  = (const float*)d_in[2];
  const float* w_out = (const float*)d_in[3];
  const float* b_out = (const float*)d_in[4];
  float* out = (float*)d_out;
  u16* ws = (u16*)d_ws;

  const size_t PH = (size_t)32 * 2048 * 64;  // 4,194,304 elems per bf16 tensor
  if (ws_size < 4 * PH * sizeof(u16)) return;
  u16* Qw  = ws;
  u16* Kw  = ws + PH;
  u16* VTw = ws + 2 * PH;
  u16* Aw  = ws + 3 * PH;

  // QKV projection: M=4096, N=3072, K=1024 (f32 in, bf16 out to ws)
  gemm_bt<0, true, true><<<dim3(24, 32), 256, 0, stream>>>(x, w_in, b_in, Qw, Kw, VTw, 1024);
  // causal flash attention (bf16 ws in/out)
  attn_kernel<<<dim3(16, 32), 256, 0, stream>>>(Qw, Kw, VTw, Aw);
  // output projection: M=4096, N=1024, K=1024 (bf16 A, f32 B, f32 out)
  gemm_bt<1, false, true><<<dim3(8, 32), 256, 0, stream>>>(Aw, w_out, b_out, out, nullptr, nullptr, 1024);
}

// Round 7
// 216.019 us; speedup vs baseline: 1.3455x; 1.3455x over previous
//
#include <hip/hip_runtime.h>
#include <hip/hip_bf16.h>
#include <stdint.h>

// B=2, S=2048, E=1024, H=16, DK=64, causal. Device buffers f32; internal bf16.

typedef __attribute__((ext_vector_type(4))) float f32x4;
typedef __attribute__((ext_vector_type(8))) __bf16 bf16x8;
typedef unsigned short u16;

#define LOG2E 1.4426950408889634f

__device__ __forceinline__ u16 f2bf(float f) {
  union { float f; uint32_t i; } v; v.f = f;
  return (u16)((v.i + 0x7fffu + ((v.i >> 16) & 1u)) >> 16);
}

__device__ __forceinline__ void gload_lds16(const u16* g, u16* l) {
  __builtin_amdgcn_global_load_lds((const __attribute__((address_space(1))) void*)g,
                                   (__attribute__((address_space(3))) void*)l, 16, 0, 0);
}

// Fragment read from [rows][64]-bf16 LDS tile, 16B-slot XOR swizzle slot^=(row&7).
__device__ __forceinline__ bf16x8 ld_frag(const u16* ls, int row, int kh, int lane) {
  int sl = ((kh << 2) | (lane >> 4)) ^ (row & 7);
  return *(const bf16x8*)(ls + row * 64 + sl * 8);
}

__device__ __forceinline__ bf16x8 cvt8(f32x4 a, f32x4 b) {
  union { u16 u[8]; bf16x8 v; } o;
#pragma unroll
  for (int j = 0; j < 4; ++j) { o.u[j] = f2bf(a[j]); o.u[4 + j] = f2bf(b[j]); }
  return o.v;
}

// f32 -> bf16 bulk convert, 8 elems/thread
__global__ __launch_bounds__(256) void cvt_f32_bf16(
    const float* __restrict__ in, u16* __restrict__ out, int n8) {
  int i = blockIdx.x * 256 + threadIdx.x;
  if (i >= n8) return;
  const f32x4* p = (const f32x4*)(in + (size_t)i * 8);
  *(bf16x8*)(out + (size_t)i * 8) = cvt8(p[0], p[1]);
}

// ---------------------------------------------------------------------------
// GEMM-BT: C[M][N] = A[M][K] * Bw[N][K]^T + bias[N]; 128x128 tile, BK=64,
// 4 waves (2x2), dbuf LDS. bf16 operands: global_load_lds w16 (pre-swizzled
// source). f32 operands: reg-stage issue-early/write-late. XCD-remapped 1D grid.
// MODE 0: N=3072 QKV -> Q[bh][s][64], K[bh][s][64], VT[bh][64][s] (bf16)
// MODE 1: N=1024 out-proj -> f32 [M][1024]
// ---------------------------------------------------------------------------
template <int MODE, bool AF32, bool BF32>
__global__ __launch_bounds__(256, 2) void gemm_bt(
    const void* Ap, const void* Bp, const float* __restrict__ bias,
    void* out0, u16* __restrict__ out1, u16* __restrict__ out2, int K, int nbn) {
  __shared__ __align__(16) u16 lsA[2][128 * 64];
  __shared__ __align__(16) u16 lsB[2][128 * 64];
  const float* Af = (const float*)Ap; const u16* Ab = (const u16*)Ap;
  const float* Bf = (const float*)Bp; const u16* Bb = (const u16*)Bp;
  const int tid = threadIdx.x, lane = tid & 63, wid = tid >> 6;
  // XCD-aware bijective remap (gridDim.x % 8 == 0)
  const int cpx = gridDim.x >> 3;
  const int wg = (blockIdx.x & 7) * cpx + (blockIdx.x >> 3);
  const int bm = wg / nbn, bn = wg % nbn;
  const int rowA0 = bm * 128, rowB0 = bn * 128;
  const int wm = wid >> 1, wn = wid & 1;

  f32x4 ra[4][2], rb[4][2];

  auto issue = [&](int buf, int k0) {
    if constexpr (AF32) {
#pragma unroll
      for (int i = 0; i < 4; ++i) {
        int u = i * 256 + tid, r = u >> 3, s = u & 7;
        const float* p = Af + (size_t)(rowA0 + r) * K + k0 + s * 8;
        ra[i][0] = *(const f32x4*)p; ra[i][1] = *(const f32x4*)(p + 4);
      }
    } else {
#pragma unroll
      for (int i = 0; i < 4; ++i) {
        int u = i * 256 + tid, r = u >> 3, s = u & 7;
        int gk = k0 + ((s ^ (r & 7)) << 3);
        gload_lds16(Ab + (size_t)(rowA0 + r) * K + gk,
                    &lsA[buf][(i * 256 + wid * 64) << 3]);
      }
    }
    if constexpr (BF32) {
#pragma unroll
      for (int i = 0; i < 4; ++i) {
        int u = i * 256 + tid, r = u >> 3, s = u & 7;
        const float* p = Bf + (size_t)(rowB0 + r) * K + k0 + s * 8;
        rb[i][0] = *(const f32x4*)p; rb[i][1] = *(const f32x4*)(p + 4);
      }
    } else {
#pragma unroll
      for (int i = 0; i < 4; ++i) {
        int u = i * 256 + tid, r = u >> 3, s = u & 7;
        int gk = k0 + ((s ^ (r & 7)) << 3);
        gload_lds16(Bb + (size_t)(rowB0 + r) * K + gk,
                    &lsB[buf][(i * 256 + wid * 64) << 3]);
      }
    }
  };
  auto commit = [&](int buf) {
    if constexpr (AF32) {
#pragma unroll
      for (int i = 0; i < 4; ++i) {
        int u = i * 256 + tid, r = u >> 3, s = u & 7;
        *(bf16x8*)&lsA[buf][r * 64 + ((s ^ (r & 7)) << 3)] = cvt8(ra[i][0], ra[i][1]);
      }
    }
    if constexpr (BF32) {
#pragma unroll
      for (int i = 0; i < 4; ++i) {
        int u = i * 256 + tid, r = u >> 3, s = u & 7;
        *(bf16x8*)&lsB[buf][r * 64 + ((s ^ (r & 7)) << 3)] = cvt8(rb[i][0], rb[i][1]);
      }
    }
  };

  f32x4 acc[4][4] = {};
  const int NT = K >> 6;
  issue(0, 0);
  commit(0);
  asm volatile("s_waitcnt vmcnt(0)" ::: "memory");
  __syncthreads();
  int cur = 0;
  for (int t = 0; t < NT; ++t) {
    if (t + 1 < NT) issue(cur ^ 1, (t + 1) << 6);
    const u16* la = lsA[cur];
    const u16* lb = lsB[cur];
    bf16x8 af[4][2], bf[4][2];
#pragma unroll
    for (int m = 0; m < 4; ++m) {
      int row = wm * 64 + m * 16 + (lane & 15);
#pragma unroll
      for (int kh = 0; kh < 2; ++kh) af[m][kh] = ld_frag(la, row, kh, lane);
    }
#pragma unroll
    for (int n = 0; n < 4; ++n) {
      int row = wn * 64 + n * 16 + (lane & 15);
#pragma unroll
      for (int kh = 0; kh < 2; ++kh) bf[n][kh] = ld_frag(lb, row, kh, lane);
    }
#pragma unroll
    for (int m = 0; m < 4; ++m)
#pragma unroll
      for (int n = 0; n < 4; ++n)
#pragma unroll
        for (int kh = 0; kh < 2; ++kh)
          acc[m][n] = __builtin_amdgcn_mfma_f32_16x16x32_bf16(af[m][kh], bf[n][kh], acc[m][n], 0, 0, 0);
    if (t + 1 < NT) commit(cur ^ 1);
    __syncthreads();
    cur ^= 1;
  }

#pragma unroll
  for (int m = 0; m < 4; ++m) {
    int gRow0 = rowA0 + wm * 64 + m * 16 + ((lane >> 4) << 2);
#pragma unroll
    for (int n = 0; n < 4; ++n) {
      int gCol = rowB0 + wn * 64 + n * 16 + (lane & 15);
      float bv = bias[gCol];
      if (MODE == 0) {
        int sec = gCol >> 10, e = gCol & 1023;
        int h = e >> 6, d = e & 63;
        int b = gRow0 >> 11, s0 = gRow0 & 2047;
        int bh = b * 16 + h;
        if (sec == 2) {
          union { u16 u[4]; uint64_t q; } pk;
#pragma unroll
          for (int r = 0; r < 4; ++r) pk.u[r] = f2bf(acc[m][n][r] + bv);
          *(uint64_t*)&out2[((size_t)bh * 64 + d) * 2048 + s0] = pk.q;
        } else {
          u16* dst = (sec == 0) ? (u16*)out0 : out1;
#pragma unroll
          for (int r = 0; r < 4; ++r)
            dst[((size_t)bh * 2048 + (s0 + r)) * 64 + d] = f2bf(acc[m][n][r] + bv);
        }
      } else {
        float* O = (float*)out0;
#pragma unroll
        for (int r = 0; r < 4; ++r)
          O[(size_t)(gRow0 + r) * 1024 + gCol] = acc[m][n][r] + bv;
      }
    }
  }
}

// ---------------------------------------------------------------------------
// Flash attention, causal. QBLK=64: block=(qt,bh), 4 waves x 16 q-rows.
// 1024 blocks, heavy-first (qt descending). LDS 40KB -> 4 blocks/CU.
// ---------------------------------------------------------------------------
__global__ __launch_bounds__(256, 4) void attn_kernel(
    const u16* __restrict__ Q, const u16* __restrict__ Kt,
    const u16* __restrict__ VT, u16* __restrict__ attn) {
  __shared__ __align__(16) u16 lsK[2][64 * 64];
  __shared__ __align__(16) u16 lsV[2][64 * 64];
  __shared__ __align__(16) u16 lsP[64 * 64];
  const int tid = threadIdx.x, lane = tid & 63, wid = tid >> 6;
  const int idx = blockIdx.x;
  const int qt = 31 - (idx >> 5);     // heavy blocks dispatched first
  const int bh = idx & 31;
  const int b = bh >> 4, h = bh & 15;
  const u16* Qb = Q + (size_t)bh * 2048 * 64;
  const u16* Kb = Kt + (size_t)bh * 2048 * 64;
  const u16* Vb = VT + (size_t)bh * 64 * 2048;
  const int qRow0 = qt * 64 + wid * 16;

  bf16x8 qf[2];
#pragma unroll
  for (int kh = 0; kh < 2; ++kh) {
    int row = qRow0 + (lane & 15);
    int d0 = kh * 32 + ((lane >> 4) << 3);
    qf[kh] = *(const bf16x8*)(Qb + (size_t)row * 64 + d0);
  }

  float rowmax[4], rowsum[4];
  f32x4 acc_o[4] = {};
#pragma unroll
  for (int r = 0; r < 4; ++r) { rowmax[r] = -1e30f; rowsum[r] = 0.f; }

  auto stageKV = [&](int buf, int kt) {
#pragma unroll
    for (int i = 0; i < 2; ++i) {
      int u = i * 256 + tid, r = u >> 3, s = u & 7;
      int gk = ((s ^ (r & 7)) << 3);
      gload_lds16(Kb + (size_t)(kt * 64 + r) * 64 + gk,
                  &lsK[buf][(i * 256 + wid * 64) << 3]);
    }
#pragma unroll
    for (int i = 0; i < 2; ++i) {
      int u = i * 256 + tid, r = u >> 3, s = u & 7;
      int gk = kt * 64 + ((s ^ (r & 7)) << 3);
      gload_lds16(Vb + (size_t)r * 2048 + gk,
                  &lsV[buf][(i * 256 + wid * 64) << 3]);
    }
  };

  const int NT = qt + 1;
  stageKV(0, 0);
  asm volatile("s_waitcnt vmcnt(0)" ::: "memory");
  __syncthreads();
  int cur = 0;
  for (int kt = 0; kt < NT; ++kt) {
    if (kt + 1 < NT) stageKV(cur ^ 1, kt + 1);

    f32x4 sc[4] = {};
    bf16x8 kf[4][2];
#pragma unroll
    for (int n = 0; n < 4; ++n) {
      int row = n * 16 + (lane & 15);
#pragma unroll
      for (int kh = 0; kh < 2; ++kh) kf[n][kh] = ld_frag(lsK[cur], row, kh, lane);
    }
#pragma unroll
    for (int n = 0; n < 4; ++n)
#pragma unroll
      for (int kh = 0; kh < 2; ++kh)
        sc[n] = __builtin_amdgcn_mfma_f32_16x16x32_bf16(qf[kh], kf[n][kh], sc[n], 0, 0, 0);

    const bool maskTile = (kt == qt);
    float tmax[4];
#pragma unroll
    for (int r = 0; r < 4; ++r) tmax[r] = -1e30f;
#pragma unroll
    for (int n = 0; n < 4; ++n)
#pragma unroll
      for (int r = 0; r < 4; ++r) {
        float s = sc[n][r] * 0.125f;
        if (maskTile) {
          int qrow = qRow0 + ((lane >> 4) << 2) + r;
          int kcol = kt * 64 + n * 16 + (lane & 15);
          if (kcol > qrow) s = -1e30f;
        }
        sc[n][r] = s;
        tmax[r] = fmaxf(tmax[r], s);
      }
#pragma unroll
    for (int r = 0; r < 4; ++r) {
      float v = tmax[r];
      v = fmaxf(v, __shfl_xor(v, 1));
      v = fmaxf(v, __shfl_xor(v, 2));
      v = fmaxf(v, __shfl_xor(v, 4));
      v = fmaxf(v, __shfl_xor(v, 8));
      tmax[r] = v;
    }

    float psum[4] = {0.f, 0.f, 0.f, 0.f};
#pragma unroll
    for (int r = 0; r < 4; ++r) {
      float mnew = fmaxf(rowmax[r], tmax[r]);
      float rs = exp2f((rowmax[r] - mnew) * LOG2E);
      rowmax[r] = mnew;
      rowsum[r] *= rs;
#pragma unroll
      for (int n = 0; n < 4; ++n) acc_o[n][r] *= rs;
    }
#pragma unroll
    for (int n = 0; n < 4; ++n)
#pragma unroll
      for (int r = 0; r < 4; ++r) {
        float p = exp2f((sc[n][r] - rowmax[r]) * LOG2E);
        psum[r] += p;
        int rowl = wid * 16 + ((lane >> 4) << 2) + r;
        int col = n * 16 + (lane & 15);
        int sl = (col >> 3) ^ (rowl & 7);
        lsP[rowl * 64 + sl * 8 + (col & 7)] = f2bf(p);
      }
#pragma unroll
    for (int r = 0; r < 4; ++r) {
      float v = psum[r];
      v += __shfl_xor(v, 1); v += __shfl_xor(v, 2);
      v += __shfl_xor(v, 4); v += __shfl_xor(v, 8);
      rowsum[r] += v;
    }

    bf16x8 pf[2], vf[4][2];
#pragma unroll
    for (int n = 0; n < 4; ++n) {
      int row = n * 16 + (lane & 15);
#pragma unroll
      for (int kh = 0; kh < 2; ++kh) vf[n][kh] = ld_frag(lsV[cur], row, kh, lane);
    }
#pragma unroll
    for (int kh = 0; kh < 2; ++kh)
      pf[kh] = ld_frag(lsP, wid * 16 + (lane & 15), kh, lane);
#pragma unroll
    for (int n = 0; n < 4; ++n)
#pragma unroll
      for (int kh = 0; kh < 2; ++kh)
        acc_o[n] = __builtin_amdgcn_mfma_f32_16x16x32_bf16(pf[kh], vf[n][kh], acc_o[n], 0, 0, 0);

    __syncthreads();
    cur ^= 1;
  }

#pragma unroll
  for (int r = 0; r < 4; ++r) {
    float inv = 1.0f / rowsum[r];
    int srow = qt * 64 + wid * 16 + ((lane >> 4) << 2) + r;
#pragma unroll
    for (int n = 0; n < 4; ++n) {
      int d = n * 16 + (lane & 15);
      attn[((size_t)(b * 2048 + srow)) * 1024 + h * 64 + d] = f2bf(acc_o[n][r] * inv);
    }
  }
}

extern "C" void kernel_launch(void* const* d_in, const int* in_sizes, int n_in,
                              void* d_out, int out_size, void* d_ws, size_t ws_size,
                              hipStream_t stream) {
  const float* x     = (const float*)d_in[0];
  const float* w_in  = (const float*)d_in[1];
  const float* b_in  = (const float*)d_in[2];
  const float* w_out = (const float*)d_in[3];
  const float* b_out = (const float*)d_in[4];
  float* out = (float*)d_out;
  u16* ws = (u16*)d_ws;

  const size_t PH = (size_t)32 * 2048 * 64;      // 4,194,304 elems
  const size_t NW_IN = (size_t)3072 * 1024;      // 3,145,728
  const size_t NW_OUT = (size_t)1024 * 1024;     // 1,048,576
  const size_t need_big = (4 * PH + NW_IN + NW_OUT) * sizeof(u16);  // ~41.8MB

  u16* Qw  = ws;
  u16* Kw  = ws + PH;
  u16* VTw = ws + 2 * PH;
  u16* Aw  = ws + 3 * PH;   // also holds xbf during GEMM1 (sequentially safe)

  if (ws_size >= need_big) {
    u16* xbf = Aw;
    u16* wibf = ws + 4 * PH;
    u16* wobf = wibf + NW_IN;
    cvt_f32_bf16<<<dim3((int)(PH / 8 / 256)), 256, 0, stream>>>(x, xbf, (int)(PH / 8));
    cvt_f32_bf16<<<dim3((int)(NW_IN / 8 / 256)), 256, 0, stream>>>(w_in, wibf, (int)(NW_IN / 8));
    cvt_f32_bf16<<<dim3((int)(NW_OUT / 8 / 256)), 256, 0, stream>>>(w_out, wobf, (int)(NW_OUT / 8));
    gemm_bt<0, false, false><<<dim3(768), 256, 0, stream>>>(xbf, wibf, b_in, Qw, Kw, VTw, 1024, 24);
    attn_kernel<<<dim3(1024), 256, 0, stream>>>(Qw, Kw, VTw, Aw);
    gemm_bt<1, false, false><<<dim3(256), 256, 0, stream>>>(Aw, wobf, b_out, out, nullptr, nullptr, 1024, 8);
  } else {
    if (ws_size < 4 * PH * sizeof(u16)) return;
    gemm_bt<0, true, true><<<dim3(768), 256, 0, stream>>>(x, w_in, b_in, Qw, Kw, VTw, 1024, 24);
    attn_kernel<<<dim3(1024), 256, 0, stream>>>(Qw, Kw, VTw, Aw);
    gemm_bt<1, false, true><<<dim3(256), 256, 0, stream>>>(Aw, w_out, b_out, out, nullptr, nullptr, 1024, 8);
  }
}